// Round 1
// baseline (784.072 us; speedup 1.0000x reference)
//
#include <hip/hip_runtime.h>
#include <hip/hip_bf16.h>

#define DI __device__ __forceinline__

typedef float f32x4 __attribute__((ext_vector_type(4)));
typedef short s16x8 __attribute__((ext_vector_type(8)));

DI short f2bf(float x) {
  union { float f; unsigned u; } v; v.f = x;
  unsigned r = v.u + 0x7fffu + ((v.u >> 16) & 1u);
  return (short)(r >> 16);
}

DI float gelu_f(float x) {
  return 0.5f * x * (1.0f + erff(x * 0.70710678118654752f));
}

DI f32x4 mfma16(s16x8 a, s16x8 b, f32x4 c) {
  return __builtin_amdgcn_mfma_f32_16x16x32_bf16(a, b, c, 0, 0, 0);
}

// ---------------------------------------------------------------------------
// Weight prep: fp32 [K][N] -> bf16 [N][K] (transposed) so MFMA B-frags are
// contiguous 16B loads per lane.
// ---------------------------------------------------------------------------
__global__ __launch_bounds__(256) void prep_kernel(
    const float* __restrict__ pfnW1, const float* __restrict__ pfnW2,
    const float* __restrict__ pffW1, const float* __restrict__ pffW2,
    short* __restrict__ W1T, short* __restrict__ W2T,
    short* __restrict__ W1Tp, short* __restrict__ W2Tp) {
  int idx = blockIdx.x * 256 + threadIdx.x;
  if (idx < 163840) {  // pfn_W1 [640][256] -> [256][640]
    int n = idx / 640, k = idx % 640;
    W1T[idx] = f2bf(pfnW1[k * 256 + n]);
    return;
  }
  idx -= 163840;
  if (idx < 32768) {   // pfn_W2 [256][128] -> [128][256]
    int n = idx / 256, k = idx % 256;
    W2T[idx] = f2bf(pfnW2[k * 128 + n]);
    return;
  }
  idx -= 32768;
  if (idx < 65536) {   // pff_W1 [128][512] -> [512][128]
    int n = idx / 128, k = idx % 128;
    W1Tp[idx] = f2bf(pffW1[k * 512 + n]);
    return;
  }
  idx -= 65536;
  if (idx < 65536) {   // pff_W2 [512][128] -> [128][512]
    int n = idx / 512, k = idx % 512;
    W2Tp[idx] = f2bf(pffW2[k * 128 + n]);
  }
}

// ---------------------------------------------------------------------------
// Context reductions: out_ctx[b,i,:] = sum_j em*pair / max(deg,1)
//                     in_ctx[b,j,:]  = sum_i em*pair / max(deg,1)
// wg < 1024: out-mode (x=i), wg >= 1024: in-mode (x=j).
// ---------------------------------------------------------------------------
__global__ __launch_bounds__(256) void ctx_kernel(
    const float* __restrict__ pair_h, const int* __restrict__ edge_mask,
    float* __restrict__ out_ctx, float* __restrict__ in_ctx) {
  __shared__ float sacc[2][128];
  __shared__ float sdeg[2];
  const int wg = blockIdx.x;
  const int t = threadIdx.x;
  const int half = t >> 7, d = t & 127;
  const bool outmode = wg < 1024;
  const int w2 = outmode ? wg : wg - 1024;
  const int b = w2 >> 8, x = w2 & 255;

  float acc = 0.f, deg = 0.f;
  for (int y0 = 0; y0 < 256; y0 += 2) {
    const int y = y0 + half;
    int row;
    int m;
    if (outmode) {
      row = (b * 256 + x) * 256 + y;
      m = edge_mask[row];
    } else {
      row = (b * 256 + y) * 256 + x;
      m = edge_mask[row];
    }
    if (m) {
      acc += pair_h[(long)row * 128 + d];
      deg += 1.f;
    }
  }
  sacc[half][d] = acc;
  if (d == 0) sdeg[half] = deg;
  __syncthreads();
  if (t < 128) {
    float tot = sacc[0][d] + sacc[1][d];
    float dg = fmaxf(sdeg[0] + sdeg[1], 1.f);
    float* dst = outmode ? out_ctx : in_ctx;
    dst[(b * 256 + x) * 128 + d] = tot / dg;
  }
}

// ---------------------------------------------------------------------------
// Node path, fully fp32. 4 waves/block, 2 rows per wave, 8 rows/block.
// ---------------------------------------------------------------------------
__global__ __launch_bounds__(256) void node_kernel(
    const float* __restrict__ node_h, const float* __restrict__ out_ctx,
    const float* __restrict__ in_ctx, const int* __restrict__ node_mask,
    const float* __restrict__ ogW, const float* __restrict__ ogb,
    const float* __restrict__ igW, const float* __restrict__ igb,
    const float* __restrict__ nW1, const float* __restrict__ nb1,
    const float* __restrict__ nW2, const float* __restrict__ nb2,
    const float* __restrict__ fW1, const float* __restrict__ fb1,
    const float* __restrict__ fW2, const float* __restrict__ fb2,
    const float* __restrict__ g1, const float* __restrict__ be1,
    const float* __restrict__ g2, const float* __restrict__ be2,
    float* __restrict__ out_node) {
  __shared__ float sh[4][1792];  // per wave: xn[2][128], xo, xi, hh[2][512]
  const int t = threadIdx.x;
  const int wv = t >> 6, lane = t & 63;
  float* const xn = sh[wv];
  float* const xo = sh[wv] + 256;
  float* const xi = sh[wv] + 512;
  float* const hh = sh[wv] + 768;
  const int row0 = blockIdx.x * 8 + wv * 2;

#pragma unroll
  for (int r = 0; r < 2; ++r) {
    const int row = row0 + r;
#pragma unroll
    for (int c = 0; c < 2; ++c) {
      const int col = lane + 64 * c;
      xn[r * 128 + col] = node_h[row * 128 + col];
      xo[r * 128 + col] = out_ctx[row * 128 + col];
      xi[r * 128 + col] = in_ctx[row * 128 + col];
    }
  }
  __syncthreads();

  // gates (sigmoid(cat(node, ctx) @ W + b)), then gate ctx in place
  {
    float ao[2][2], ai[2][2];
#pragma unroll
    for (int c = 0; c < 2; ++c) {
      const int col = lane + 64 * c;
      ao[0][c] = ao[1][c] = ogb[col];
      ai[0][c] = ai[1][c] = igb[col];
    }
    for (int k = 0; k < 256; ++k) {
      float xo0, xo1, xi0, xi1;
      if (k < 128) {
        xo0 = xi0 = xn[k];
        xo1 = xi1 = xn[128 + k];
      } else {
        xo0 = xo[k - 128]; xo1 = xo[k];
        xi0 = xi[k - 128]; xi1 = xi[k];
      }
#pragma unroll
      for (int c = 0; c < 2; ++c) {
        const int col = lane + 64 * c;
        const float wo = ogW[k * 128 + col], wi = igW[k * 128 + col];
        ao[0][c] += xo0 * wo; ao[1][c] += xo1 * wo;
        ai[0][c] += xi0 * wi; ai[1][c] += xi1 * wi;
      }
    }
#pragma unroll
    for (int c = 0; c < 2; ++c) {
      const int col = lane + 64 * c;
#pragma unroll
      for (int r = 0; r < 2; ++r) {
        const float go = 1.f / (1.f + __expf(-ao[r][c]));
        const float gi = 1.f / (1.f + __expf(-ai[r][c]));
        xo[r * 128 + col] *= go;
        xi[r * 128 + col] *= gi;
      }
    }
  }
  __syncthreads();

  // nfp MLP: [node, gated_out, gated_in] (384) -> 256 gelu -> 128
  {
    float a1[2][4];
#pragma unroll
    for (int c = 0; c < 4; ++c) {
      const int col = lane + 64 * c;
      a1[0][c] = a1[1][c] = nb1[col];
    }
    for (int k = 0; k < 384; ++k) {
      const float* src = (k < 128) ? xn : (k < 256) ? xo : xi;
      const int kk = k & 127;
      const float x0 = src[kk], x1 = src[128 + kk];
#pragma unroll
      for (int c = 0; c < 4; ++c) {
        const int col = lane + 64 * c;
        const float w = nW1[k * 256 + col];
        a1[0][c] += x0 * w; a1[1][c] += x1 * w;
      }
    }
#pragma unroll
    for (int c = 0; c < 4; ++c) {
      const int col = lane + 64 * c;
      hh[col] = gelu_f(a1[0][c]);
      hh[512 + col] = gelu_f(a1[1][c]);
    }
  }
  __syncthreads();
  {
    float a2[2][2];
#pragma unroll
    for (int c = 0; c < 2; ++c) {
      const int col = lane + 64 * c;
      a2[0][c] = a2[1][c] = nb2[col];
    }
    for (int k = 0; k < 256; ++k) {
      const float h0 = hh[k], h1 = hh[512 + k];
#pragma unroll
      for (int c = 0; c < 2; ++c) {
        const int col = lane + 64 * c;
        const float w = nW2[k * 128 + col];
        a2[0][c] += h0 * w; a2[1][c] += h1 * w;
      }
    }
    // residual + LN1 (in-wave shuffle reduce over 128 vals)
#pragma unroll
    for (int r = 0; r < 2; ++r) {
      float v0 = xn[r * 128 + lane] + a2[r][0];
      float v1 = xn[r * 128 + lane + 64] + a2[r][1];
      float s = v0 + v1, ss = v0 * v0 + v1 * v1;
#pragma unroll
      for (int off = 1; off < 64; off <<= 1) {
        s += __shfl_xor(s, off, 64);
        ss += __shfl_xor(ss, off, 64);
      }
      const float m = s * (1.f / 128.f);
      const float var = ss * (1.f / 128.f) - m * m;
      const float rs = rsqrtf(var + 1e-5f);
      xn[r * 128 + lane] = (v0 - m) * rs * g1[lane] + be1[lane];
      xn[r * 128 + lane + 64] = (v1 - m) * rs * g1[lane + 64] + be1[lane + 64];
    }
  }
  __syncthreads();

  // nff: 128 -> 512 gelu -> 128
  {
    float af[2][8];
#pragma unroll
    for (int c = 0; c < 8; ++c) {
      const int col = lane + 64 * c;
      af[0][c] = af[1][c] = fb1[col];
    }
    for (int k = 0; k < 128; ++k) {
      const float x0 = xn[k], x1 = xn[128 + k];
#pragma unroll
      for (int c = 0; c < 8; ++c) {
        const int col = lane + 64 * c;
        const float w = fW1[k * 512 + col];
        af[0][c] += x0 * w; af[1][c] += x1 * w;
      }
    }
#pragma unroll
    for (int c = 0; c < 8; ++c) {
      const int col = lane + 64 * c;
      hh[col] = gelu_f(af[0][c]);
      hh[512 + col] = gelu_f(af[1][c]);
    }
  }
  __syncthreads();
  {
    float a2[2][2];
#pragma unroll
    for (int c = 0; c < 2; ++c) {
      const int col = lane + 64 * c;
      a2[0][c] = a2[1][c] = fb2[col];
    }
    for (int k = 0; k < 512; ++k) {
      const float h0 = hh[k], h1 = hh[512 + k];
#pragma unroll
      for (int c = 0; c < 2; ++c) {
        const int col = lane + 64 * c;
        const float w = fW2[k * 128 + col];
        a2[0][c] += h0 * w; a2[1][c] += h1 * w;
      }
    }
#pragma unroll
    for (int r = 0; r < 2; ++r) {
      const int row = row0 + r;
      float v0 = xn[r * 128 + lane] + a2[r][0];
      float v1 = xn[r * 128 + lane + 64] + a2[r][1];
      float s = v0 + v1, ss = v0 * v0 + v1 * v1;
#pragma unroll
      for (int off = 1; off < 64; off <<= 1) {
        s += __shfl_xor(s, off, 64);
        ss += __shfl_xor(ss, off, 64);
      }
      const float m = s * (1.f / 128.f);
      const float var = ss * (1.f / 128.f) - m * m;
      const float rs = rsqrtf(var + 1e-5f);
      const float msk = (float)node_mask[row];
      out_node[row * 128 + lane] =
          ((v0 - m) * rs * g2[lane] + be2[lane]) * msk;
      out_node[row * 128 + lane + 64] =
          ((v1 - m) * rs * g2[lane + 64] + be2[lane + 64]) * msk;
    }
  }
}

// ---------------------------------------------------------------------------
// Fused pair kernel. One WG (512 thr = 8 waves) per 64-row tile (fixed b,i;
// 64 consecutive j). LDS arena (117KB, phase-overlaid):
//   FEAT  bf16 [64][648] @0        (pitch 1296B = 324 banks == 4 mod 32)
//   H1    bf16 [64][264] @0        (after GEMM1; pitch 528B)
//   YB    bf16 [64][136] @34048    (LN1 out;    pitch 272B)
//   H2    bf16 [64][520] @0        (after GEMM3; pitch 1040B)
//   PAIR  f32  [64][132] @82944    (residual -> x1 -> y -> x2; pitch 528B)
//   VP    f32  [64]      @116736
// ---------------------------------------------------------------------------
__global__ __launch_bounds__(512) void pair_kernel(
    const float* __restrict__ pair_h, const float* __restrict__ node_f,
    const int* __restrict__ edge_mask,
    const short* __restrict__ W1T, const short* __restrict__ W2T,
    const short* __restrict__ W1Tp, const short* __restrict__ W2Tp,
    const float* __restrict__ b1, const float* __restrict__ b2,
    const float* __restrict__ b1p, const float* __restrict__ b2p,
    const float* __restrict__ g1, const float* __restrict__ be1,
    const float* __restrict__ g2, const float* __restrict__ be2,
    float* __restrict__ out_pair) {
  constexpr int OFF_PAIR = 82944;
  constexpr int OFF_VP = 116736;
  __shared__ __align__(16) char smem[116992];

  const int t = threadIdx.x;
  const int wg = blockIdx.x;
  const int b = wg >> 10;
  const int rem = wg & 1023;
  const int i = rem >> 2;
  const int j0 = (rem & 3) << 6;
  const int bi = (b << 8) + i;
  const long rowbase = (long)bi * 256 + j0;

  // ---- P0: build feat tile + fp32 pair residual + vp ----
  {
    const int r = t >> 3;
    const int oc = t & 7;
    const float* prow = pair_h + (rowbase + r) * 128;
    const float* hjrow = node_f + (b * 256 + j0 + r) * 128;
    const float* hirow = node_f + (b * 256 + i) * 128;
    short* feat = (short*)(smem) + r * 648;
    float* pres = (float*)(smem + OFF_PAIR) + r * 132;
#pragma unroll
    for (int half = 0; half < 2; ++half) {
      const int c = (oc + half * 8) * 8;
      f32x4 p0 = *(const f32x4*)(prow + c);
      f32x4 p1 = *(const f32x4*)(prow + c + 4);
      f32x4 a0 = *(const f32x4*)(hirow + c);
      f32x4 a1 = *(const f32x4*)(hirow + c + 4);
      f32x4 q0 = *(const f32x4*)(hjrow + c);
      f32x4 q1 = *(const f32x4*)(hjrow + c + 4);
      *(f32x4*)(pres + c) = p0;
      *(f32x4*)(pres + c + 4) = p1;
      s16x8 sp, shi, shj, sd, sm;
#pragma unroll
      for (int e = 0; e < 4; ++e) {
        sp[e] = f2bf(p0[e]);          sp[e + 4] = f2bf(p1[e]);
        shi[e] = f2bf(a0[e]);         shi[e + 4] = f2bf(a1[e]);
        shj[e] = f2bf(q0[e]);         shj[e + 4] = f2bf(q1[e]);
        sd[e] = f2bf(a0[e] - q0[e]);  sd[e + 4] = f2bf(a1[e] - q1[e]);
        sm[e] = f2bf(a0[e] * q0[e]);  sm[e + 4] = f2bf(a1[e] * q1[e]);
      }
      *(s16x8*)(feat + c) = sp;
      *(s16x8*)(feat + 128 + c) = shi;
      *(s16x8*)(feat + 256 + c) = shj;
      *(s16x8*)(feat + 384 + c) = sd;
      *(s16x8*)(feat + 512 + c) = sm;
    }
    if (t < 64)
      ((float*)(smem + OFF_VP))[t] = (float)edge_mask[(long)bi * 256 + j0 + t];
  }
  __syncthreads();

  const int lane = t & 63;
  const int wv = t >> 6;
  const int lr = lane & 15;
  const int lq = lane >> 4;

  // ---- GEMM1: C1[64][256] = FEAT[64][640] @ W1; wave wv -> cols [32wv,32wv+32)
  f32x4 acc1[4][2];
#pragma unroll
  for (int m = 0; m < 4; ++m)
#pragma unroll
    for (int n = 0; n < 2; ++n) acc1[m][n] = {0.f, 0.f, 0.f, 0.f};
  {
    const int n0 = wv * 32;
    const short* bptr0 = W1T + (n0 + lr) * 640 + lq * 8;
    const short* bptr1 = W1T + (n0 + 16 + lr) * 640 + lq * 8;
    const char* abase = smem + lr * 1296 + lq * 16;
    s16x8 bc0 = *(const s16x8*)(bptr0);
    s16x8 bc1 = *(const s16x8*)(bptr1);
#pragma unroll
    for (int ks = 0; ks < 20; ++ks) {
      s16x8 bn0 = bc0, bn1 = bc1;
      if (ks < 19) {
        bn0 = *(const s16x8*)(bptr0 + (ks + 1) * 32);
        bn1 = *(const s16x8*)(bptr1 + (ks + 1) * 32);
      }
      s16x8 a[4];
#pragma unroll
      for (int m = 0; m < 4; ++m)
        a[m] = *(const s16x8*)(abase + m * 16 * 1296 + ks * 64);
#pragma unroll
      for (int m = 0; m < 4; ++m) {
        acc1[m][0] = mfma16(a[m], bc0, acc1[m][0]);
        acc1[m][1] = mfma16(a[m], bc1, acc1[m][1]);
      }
      bc0 = bn0; bc1 = bn1;
    }
  }
  __syncthreads();  // FEAT dead -> H1 may overlay
  {
    const int n0 = wv * 32;
#pragma unroll
    for (int n = 0; n < 2; ++n) {
      const int col = n0 + n * 16 + lr;
      const float bias = b1[col];
#pragma unroll
      for (int m = 0; m < 4; ++m)
#pragma unroll
        for (int v = 0; v < 4; ++v) {
          const int row = m * 16 + lq * 4 + v;
          ((short*)smem)[row * 264 + col] = f2bf(gelu_f(acc1[m][n][v] + bias));
        }
    }
  }
  __syncthreads();

  // ---- GEMM2: upd[64][128] = H1[64][256] @ W2 ----
  const int wm = wv >> 2, wn = wv & 3;
  {
    f32x4 acc2[2][2];
#pragma unroll
    for (int m = 0; m < 2; ++m)
#pragma unroll
      for (int n = 0; n < 2; ++n) acc2[m][n] = {0.f, 0.f, 0.f, 0.f};
    const int r0 = wm * 32, n0 = wn * 32;
    const short* bp0 = W2T + (n0 + lr) * 256 + lq * 8;
    const short* bp1 = W2T + (n0 + 16 + lr) * 256 + lq * 8;
    const char* ab = smem + (r0 + lr) * 528 + lq * 16;
    s16x8 bc0 = *(const s16x8*)bp0;
    s16x8 bc1 = *(const s16x8*)bp1;
#pragma unroll
    for (int ks = 0; ks < 8; ++ks) {
      s16x8 bn0 = bc0, bn1 = bc1;
      if (ks < 7) {
        bn0 = *(const s16x8*)(bp0 + (ks + 1) * 32);
        bn1 = *(const s16x8*)(bp1 + (ks + 1) * 32);
      }
      s16x8 a0 = *(const s16x8*)(ab + ks * 64);
      s16x8 a1 = *(const s16x8*)(ab + 16 * 528 + ks * 64);
      acc2[0][0] = mfma16(a0, bc0, acc2[0][0]);
      acc2[0][1] = mfma16(a0, bc1, acc2[0][1]);
      acc2[1][0] = mfma16(a1, bc0, acc2[1][0]);
      acc2[1][1] = mfma16(a1, bc1, acc2[1][1]);
      bc0 = bn0; bc1 = bn1;
    }
    // x1 = pair + upd + b2 (in place into PAIR region)
    float* pres = (float*)(smem + OFF_PAIR);
#pragma unroll
    for (int n = 0; n < 2; ++n) {
      const int col = wn * 32 + n * 16 + lr;
      const float bias = b2[col];
#pragma unroll
      for (int m = 0; m < 2; ++m)
#pragma unroll
        for (int v = 0; v < 4; ++v) {
          const int row = wm * 32 + m * 16 + lq * 4 + v;
          pres[row * 132 + col] += acc2[m][n][v] + bias;
        }
    }
  }
  __syncthreads();

  // ---- LN1: y = LN(x1); y fp32 in place, y bf16 -> YB ----
  {
    const int r = t >> 3, cg = (t & 7) * 16;
    float* xr = (float*)(smem + OFF_PAIR) + r * 132;
    f32x4 x[4];
#pragma unroll
    for (int q = 0; q < 4; ++q) x[q] = *(const f32x4*)(xr + cg + q * 4);
    float s = 0.f, ss = 0.f;
#pragma unroll
    for (int q = 0; q < 4; ++q)
#pragma unroll
      for (int e = 0; e < 4; ++e) { s += x[q][e]; ss += x[q][e] * x[q][e]; }
#pragma unroll
    for (int off = 1; off < 8; off <<= 1) {
      s += __shfl_xor(s, off, 64);
      ss += __shfl_xor(ss, off, 64);
    }
    const float m = s * (1.f / 128.f);
    const float var = ss * (1.f / 128.f) - m * m;
    const float rs = rsqrtf(var + 1e-5f);
    short* yb = (short*)(smem + 34048) + r * 136;
    s16x8 pk0, pk1;
#pragma unroll
    for (int q = 0; q < 4; ++q) {
      f32x4 gv = *(const f32x4*)(g1 + cg + q * 4);
      f32x4 bv = *(const f32x4*)(be1 + cg + q * 4);
      f32x4 y;
#pragma unroll
      for (int e = 0; e < 4; ++e) {
        y[e] = (x[q][e] - m) * rs * gv[e] + bv[e];
        if (q < 2) pk0[q * 4 + e] = f2bf(y[e]);
        else pk1[(q - 2) * 4 + e] = f2bf(y[e]);
      }
      *(f32x4*)(xr + cg + q * 4) = y;
    }
    *(s16x8*)(yb + cg) = pk0;
    *(s16x8*)(yb + cg + 8) = pk1;
  }
  __syncthreads();

  // ---- GEMM3: h2[64][512] = Y[64][128] @ pff_W1; wave -> cols [64wv,64wv+64)
  f32x4 acc3[4][4];
#pragma unroll
  for (int m = 0; m < 4; ++m)
#pragma unroll
    for (int n = 0; n < 4; ++n) acc3[m][n] = {0.f, 0.f, 0.f, 0.f};
  {
    const int n0 = wv * 64;
    const short* bp[4];
    s16x8 bc[4];
#pragma unroll
    for (int n = 0; n < 4; ++n) {
      bp[n] = W1Tp + (n0 + n * 16 + lr) * 128 + lq * 8;
      bc[n] = *(const s16x8*)bp[n];
    }
    const char* ab = smem + 34048 + lr * 272 + lq * 16;
#pragma unroll
    for (int ks = 0; ks < 4; ++ks) {
      s16x8 bn[4];
#pragma unroll
      for (int n = 0; n < 4; ++n) {
        bn[n] = bc[n];
        if (ks < 3) bn[n] = *(const s16x8*)(bp[n] + (ks + 1) * 32);
      }
      s16x8 a[4];
#pragma unroll
      for (int m = 0; m < 4; ++m)
        a[m] = *(const s16x8*)(ab + m * 16 * 272 + ks * 64);
#pragma unroll
      for (int m = 0; m < 4; ++m)
#pragma unroll
        for (int n = 0; n < 4; ++n) acc3[m][n] = mfma16(a[m], bc[n], acc3[m][n]);
#pragma unroll
      for (int n = 0; n < 4; ++n) bc[n] = bn[n];
    }
  }
  __syncthreads();  // YB dead -> H2 may overlay
  {
    const int n0 = wv * 64;
#pragma unroll
    for (int n = 0; n < 4; ++n) {
      const int col = n0 + n * 16 + lr;
      const float bias = b1p[col];
#pragma unroll
      for (int m = 0; m < 4; ++m)
#pragma unroll
        for (int v = 0; v < 4; ++v) {
          const int row = m * 16 + lq * 4 + v;
          ((short*)smem)[row * 520 + col] = f2bf(gelu_f(acc3[m][n][v] + bias));
        }
    }
  }
  __syncthreads();

  // ---- GEMM4: upd2[64][128] = H2[64][512] @ pff_W2 ----
  {
    f32x4 acc4[2][2];
#pragma unroll
    for (int m = 0; m < 2; ++m)
#pragma unroll
      for (int n = 0; n < 2; ++n) acc4[m][n] = {0.f, 0.f, 0.f, 0.f};
    const int r0 = wm * 32, n0 = wn * 32;
    const short* bp0 = W2Tp + (n0 + lr) * 512 + lq * 8;
    const short* bp1 = W2Tp + (n0 + 16 + lr) * 512 + lq * 8;
    const char* ab = smem + (r0 + lr) * 1040 + lq * 16;
    s16x8 bc0 = *(const s16x8*)bp0;
    s16x8 bc1 = *(const s16x8*)bp1;
#pragma unroll
    for (int ks = 0; ks < 16; ++ks) {
      s16x8 bn0 = bc0, bn1 = bc1;
      if (ks < 15) {
        bn0 = *(const s16x8*)(bp0 + (ks + 1) * 32);
        bn1 = *(const s16x8*)(bp1 + (ks + 1) * 32);
      }
      s16x8 a0 = *(const s16x8*)(ab + ks * 64);
      s16x8 a1 = *(const s16x8*)(ab + 16 * 1040 + ks * 64);
      acc4[0][0] = mfma16(a0, bc0, acc4[0][0]);
      acc4[0][1] = mfma16(a0, bc1, acc4[0][1]);
      acc4[1][0] = mfma16(a1, bc0, acc4[1][0]);
      acc4[1][1] = mfma16(a1, bc1, acc4[1][1]);
      bc0 = bn0; bc1 = bn1;
    }
    // x2 = y + upd2 + b2p (in place)
    float* pres = (float*)(smem + OFF_PAIR);
#pragma unroll
    for (int n = 0; n < 2; ++n) {
      const int col = wn * 32 + n * 16 + lr;
      const float bias = b2p[col];
#pragma unroll
      for (int m = 0; m < 2; ++m)
#pragma unroll
        for (int v = 0; v < 4; ++v) {
          const int row = wm * 32 + m * 16 + lq * 4 + v;
          pres[row * 132 + col] += acc4[m][n][v] + bias;
        }
    }
  }
  __syncthreads();

  // ---- LN2 + edge mask + store ----
  {
    const int r = t >> 3, cg = (t & 7) * 16;
    const float* xr = (const float*)(smem + OFF_PAIR) + r * 132;
    f32x4 x[4];
#pragma unroll
    for (int q = 0; q < 4; ++q) x[q] = *(const f32x4*)(xr + cg + q * 4);
    float s = 0.f, ss = 0.f;
#pragma unroll
    for (int q = 0; q < 4; ++q)
#pragma unroll
      for (int e = 0; e < 4; ++e) { s += x[q][e]; ss += x[q][e] * x[q][e]; }
#pragma unroll
    for (int off = 1; off < 8; off <<= 1) {
      s += __shfl_xor(s, off, 64);
      ss += __shfl_xor(ss, off, 64);
    }
    const float m = s * (1.f / 128.f);
    const float var = ss * (1.f / 128.f) - m * m;
    const float rs = rsqrtf(var + 1e-5f);
    const float vpf = ((const float*)(smem + OFF_VP))[r];
    float* orow = out_pair + (rowbase + r) * 128;
#pragma unroll
    for (int q = 0; q < 4; ++q) {
      f32x4 gv = *(const f32x4*)(g2 + cg + q * 4);
      f32x4 bv = *(const f32x4*)(be2 + cg + q * 4);
      f32x4 y;
#pragma unroll
      for (int e = 0; e < 4; ++e)
        y[e] = ((x[q][e] - m) * rs * gv[e] + bv[e]) * vpf;
      *(f32x4*)(orow + cg + q * 4) = y;
    }
  }
}

// ---------------------------------------------------------------------------
extern "C" void kernel_launch(void* const* d_in, const int* in_sizes, int n_in,
                              void* d_out, int out_size, void* d_ws,
                              size_t ws_size, hipStream_t stream) {
  const float* node_h = (const float*)d_in[0];
  const float* pair_h = (const float*)d_in[1];
  const int* node_mask = (const int*)d_in[2];
  const int* edge_mask = (const int*)d_in[3];
  const float* nfp_W1 = (const float*)d_in[4];
  const float* nfp_b1 = (const float*)d_in[5];
  const float* nfp_W2 = (const float*)d_in[6];
  const float* nfp_b2 = (const float*)d_in[7];
  const float* pfn_W1 = (const float*)d_in[8];
  const float* pfn_b1 = (const float*)d_in[9];
  const float* pfn_W2 = (const float*)d_in[10];
  const float* pfn_b2 = (const float*)d_in[11];
  const float* nff_W1 = (const float*)d_in[12];
  const float* nff_b1 = (const float*)d_in[13];
  const float* nff_W2 = (const float*)d_in[14];
  const float* nff_b2 = (const float*)d_in[15];
  const float* pff_W1 = (const float*)d_in[16];
  const float* pff_b1 = (const float*)d_in[17];
  const float* pff_W2 = (const float*)d_in[18];
  const float* pff_b2 = (const float*)d_in[19];
  const float* og_W = (const float*)d_in[20];
  const float* og_b = (const float*)d_in[21];
  const float* ig_W = (const float*)d_in[22];
  const float* ig_b = (const float*)d_in[23];
  const float* nn1_g = (const float*)d_in[24];
  const float* nn1_b = (const float*)d_in[25];
  const float* nn2_g = (const float*)d_in[26];
  const float* nn2_b = (const float*)d_in[27];
  const float* pn1_g = (const float*)d_in[28];
  const float* pn1_b = (const float*)d_in[29];
  const float* pn2_g = (const float*)d_in[30];
  const float* pn2_b = (const float*)d_in[31];

  char* ws = (char*)d_ws;
  short* W1T = (short*)(ws);             // 256*640*2  = 327680
  short* W2T = (short*)(ws + 327680);    // 128*256*2  = 65536
  short* W1Tp = (short*)(ws + 393216);   // 512*128*2  = 131072
  short* W2Tp = (short*)(ws + 524288);   // 128*512*2  = 131072
  float* out_ctx = (float*)(ws + 655360);   // 4*256*128*4 = 524288
  float* in_ctx = (float*)(ws + 1179648);   // 524288 -> ends 1703936

  float* out_node = (float*)d_out;
  float* out_pair = (float*)d_out + 131072;

  prep_kernel<<<1280, 256, 0, stream>>>(pfn_W1, pfn_W2, pff_W1, pff_W2, W1T,
                                        W2T, W1Tp, W2Tp);
  ctx_kernel<<<2048, 256, 0, stream>>>(pair_h, edge_mask, out_ctx, in_ctx);
  node_kernel<<<128, 256, 0, stream>>>(
      node_h, out_ctx, in_ctx, node_mask, og_W, og_b, ig_W, ig_b, nfp_W1,
      nfp_b1, nfp_W2, nfp_b2, nff_W1, nff_b1, nff_W2, nff_b2, nn1_g, nn1_b,
      nn2_g, nn2_b, out_node);
  pair_kernel<<<4096, 512, 0, stream>>>(
      pair_h, out_node, edge_mask, W1T, W2T, W1Tp, W2Tp, pfn_b1, pfn_b2,
      pff_b1, pff_b2, pn1_g, pn1_b, pn2_g, pn2_b, out_pair);
}

// Round 2
// 625.424 us; speedup vs baseline: 1.2537x; 1.2537x over previous
//
#include <hip/hip_runtime.h>
#include <hip/hip_bf16.h>

#define DI __device__ __forceinline__

typedef float f32x4 __attribute__((ext_vector_type(4)));
typedef float f32x2 __attribute__((ext_vector_type(2)));
typedef short s16x8 __attribute__((ext_vector_type(8)));
typedef short s16x4 __attribute__((ext_vector_type(4)));

DI short f2bf(float x) {
  union { float f; unsigned u; } v; v.f = x;
  unsigned r = v.u + 0x7fffu + ((v.u >> 16) & 1u);
  return (short)(r >> 16);
}

DI float bf2f(short x) {
  union { unsigned u; float f; } v;
  v.u = ((unsigned)(unsigned short)x) << 16;
  return v.f;
}

DI float gelu_f(float x) {
  return 0.5f * x * (1.0f + erff(x * 0.70710678118654752f));
}

DI f32x4 mfma16(s16x8 a, s16x8 b, f32x4 c) {
  return __builtin_amdgcn_mfma_f32_16x16x32_bf16(a, b, c, 0, 0, 0);
}

// ---------------------------------------------------------------------------
// Weight prep.
//  W1b  bf16 [256 n][384 k]: k<128 -> W1[k][n]; k in [128,256) -> W1[k+128][n]
//       - W1[k+256][n]; k in [256,384) -> W1[k+256][n]   (combined hj / prod)
//  Wu   f32  [128 k][256 n]: W1[128+k][n] + W1[384+k][n] (hi coefficient)
//  W2T  bf16 [128 n][256 k], W1Tp bf16 [512 n][128 k], W2Tp bf16 [128 n][512 k]
// ---------------------------------------------------------------------------
__global__ __launch_bounds__(256) void prep_kernel(
    const float* __restrict__ pfnW1, const float* __restrict__ pfnW2,
    const float* __restrict__ pffW1, const float* __restrict__ pffW2,
    short* __restrict__ W1b, float* __restrict__ Wu, short* __restrict__ W2T,
    short* __restrict__ W1Tp, short* __restrict__ W2Tp) {
  int idx = blockIdx.x * 256 + threadIdx.x;
  if (idx < 98304) {  // W1b
    int n = idx / 384, k = idx % 384;
    float v;
    if (k < 128) v = pfnW1[k * 256 + n];
    else if (k < 256) v = pfnW1[(128 + k) * 256 + n] - pfnW1[(256 + k) * 256 + n];
    else v = pfnW1[(256 + k) * 256 + n];
    W1b[idx] = f2bf(v);
    return;
  }
  idx -= 98304;
  if (idx < 32768) {  // Wu
    int k = idx / 256, n = idx % 256;
    Wu[idx] = pfnW1[(128 + k) * 256 + n] + pfnW1[(384 + k) * 256 + n];
    return;
  }
  idx -= 32768;
  if (idx < 32768) {  // W2T
    int n = idx / 256, k = idx % 256;
    W2T[idx] = f2bf(pfnW2[k * 128 + n]);
    return;
  }
  idx -= 32768;
  if (idx < 65536) {  // W1Tp
    int n = idx / 128, k = idx % 128;
    W1Tp[idx] = f2bf(pffW1[k * 512 + n]);
    return;
  }
  idx -= 65536;
  if (idx < 65536) {  // W2Tp
    int n = idx / 512, k = idx % 512;
    W2Tp[idx] = f2bf(pffW2[k * 128 + n]);
  }
}

// ---------------------------------------------------------------------------
// Context reductions (unchanged from R1).
// ---------------------------------------------------------------------------
__global__ __launch_bounds__(256) void ctx_kernel(
    const float* __restrict__ pair_h, const int* __restrict__ edge_mask,
    float* __restrict__ out_ctx, float* __restrict__ in_ctx) {
  __shared__ float sacc[2][128];
  __shared__ float sdeg[2];
  const int wg = blockIdx.x;
  const int t = threadIdx.x;
  const int half = t >> 7, d = t & 127;
  const bool outmode = wg < 1024;
  const int w2 = outmode ? wg : wg - 1024;
  const int b = w2 >> 8, x = w2 & 255;

  float acc = 0.f, deg = 0.f;
  for (int y0 = 0; y0 < 256; y0 += 2) {
    const int y = y0 + half;
    int row;
    if (outmode) row = (b * 256 + x) * 256 + y;
    else row = (b * 256 + y) * 256 + x;
    const int m = edge_mask[row];
    if (m) {
      acc += pair_h[(long)row * 128 + d];
      deg += 1.f;
    }
  }
  sacc[half][d] = acc;
  if (d == 0) sdeg[half] = deg;
  __syncthreads();
  if (t < 128) {
    float tot = sacc[0][d] + sacc[1][d];
    float dg = fmaxf(sdeg[0] + sdeg[1], 1.f);
    float* dst = outmode ? out_ctx : in_ctx;
    dst[(b * 256 + x) * 128 + d] = tot / dg;
  }
}

// ---------------------------------------------------------------------------
// Node path, fp32 (unchanged except bf16 copy-out for the pair kernel).
// ---------------------------------------------------------------------------
__global__ __launch_bounds__(256) void node_kernel(
    const float* __restrict__ node_h, const float* __restrict__ out_ctx,
    const float* __restrict__ in_ctx, const int* __restrict__ node_mask,
    const float* __restrict__ ogW, const float* __restrict__ ogb,
    const float* __restrict__ igW, const float* __restrict__ igb,
    const float* __restrict__ nW1, const float* __restrict__ nb1,
    const float* __restrict__ nW2, const float* __restrict__ nb2,
    const float* __restrict__ fW1, const float* __restrict__ fb1,
    const float* __restrict__ fW2, const float* __restrict__ fb2,
    const float* __restrict__ g1, const float* __restrict__ be1,
    const float* __restrict__ g2, const float* __restrict__ be2,
    float* __restrict__ out_node, short* __restrict__ node_bf) {
  __shared__ float sh[4][1792];
  const int t = threadIdx.x;
  const int wv = t >> 6, lane = t & 63;
  float* const xn = sh[wv];
  float* const xo = sh[wv] + 256;
  float* const xi = sh[wv] + 512;
  float* const hh = sh[wv] + 768;
  const int row0 = blockIdx.x * 8 + wv * 2;

#pragma unroll
  for (int r = 0; r < 2; ++r) {
    const int row = row0 + r;
#pragma unroll
    for (int c = 0; c < 2; ++c) {
      const int col = lane + 64 * c;
      xn[r * 128 + col] = node_h[row * 128 + col];
      xo[r * 128 + col] = out_ctx[row * 128 + col];
      xi[r * 128 + col] = in_ctx[row * 128 + col];
    }
  }
  __syncthreads();

  {
    float ao[2][2], ai[2][2];
#pragma unroll
    for (int c = 0; c < 2; ++c) {
      const int col = lane + 64 * c;
      ao[0][c] = ao[1][c] = ogb[col];
      ai[0][c] = ai[1][c] = igb[col];
    }
    for (int k = 0; k < 256; ++k) {
      float xo0, xo1, xi0, xi1;
      if (k < 128) {
        xo0 = xi0 = xn[k];
        xo1 = xi1 = xn[128 + k];
      } else {
        xo0 = xo[k - 128]; xo1 = xo[k];
        xi0 = xi[k - 128]; xi1 = xi[k];
      }
#pragma unroll
      for (int c = 0; c < 2; ++c) {
        const int col = lane + 64 * c;
        const float wo = ogW[k * 128 + col], wi = igW[k * 128 + col];
        ao[0][c] += xo0 * wo; ao[1][c] += xo1 * wo;
        ai[0][c] += xi0 * wi; ai[1][c] += xi1 * wi;
      }
    }
#pragma unroll
    for (int c = 0; c < 2; ++c) {
      const int col = lane + 64 * c;
#pragma unroll
      for (int r = 0; r < 2; ++r) {
        const float go = 1.f / (1.f + __expf(-ao[r][c]));
        const float gi = 1.f / (1.f + __expf(-ai[r][c]));
        xo[r * 128 + col] *= go;
        xi[r * 128 + col] *= gi;
      }
    }
  }
  __syncthreads();

  {
    float a1[2][4];
#pragma unroll
    for (int c = 0; c < 4; ++c) {
      const int col = lane + 64 * c;
      a1[0][c] = a1[1][c] = nb1[col];
    }
    for (int k = 0; k < 384; ++k) {
      const float* src = (k < 128) ? xn : (k < 256) ? xo : xi;
      const int kk = k & 127;
      const float x0 = src[kk], x1 = src[128 + kk];
#pragma unroll
      for (int c = 0; c < 4; ++c) {
        const int col = lane + 64 * c;
        const float w = nW1[k * 256 + col];
        a1[0][c] += x0 * w; a1[1][c] += x1 * w;
      }
    }
#pragma unroll
    for (int c = 0; c < 4; ++c) {
      const int col = lane + 64 * c;
      hh[col] = gelu_f(a1[0][c]);
      hh[512 + col] = gelu_f(a1[1][c]);
    }
  }
  __syncthreads();
  {
    float a2[2][2];
#pragma unroll
    for (int c = 0; c < 2; ++c) {
      const int col = lane + 64 * c;
      a2[0][c] = a2[1][c] = nb2[col];
    }
    for (int k = 0; k < 256; ++k) {
      const float h0 = hh[k], h1 = hh[512 + k];
#pragma unroll
      for (int c = 0; c < 2; ++c) {
        const int col = lane + 64 * c;
        const float w = nW2[k * 128 + col];
        a2[0][c] += h0 * w; a2[1][c] += h1 * w;
      }
    }
#pragma unroll
    for (int r = 0; r < 2; ++r) {
      float v0 = xn[r * 128 + lane] + a2[r][0];
      float v1 = xn[r * 128 + lane + 64] + a2[r][1];
      float s = v0 + v1, ss = v0 * v0 + v1 * v1;
#pragma unroll
      for (int off = 1; off < 64; off <<= 1) {
        s += __shfl_xor(s, off, 64);
        ss += __shfl_xor(ss, off, 64);
      }
      const float m = s * (1.f / 128.f);
      const float var = ss * (1.f / 128.f) - m * m;
      const float rs = rsqrtf(var + 1e-5f);
      xn[r * 128 + lane] = (v0 - m) * rs * g1[lane] + be1[lane];
      xn[r * 128 + lane + 64] = (v1 - m) * rs * g1[lane + 64] + be1[lane + 64];
    }
  }
  __syncthreads();

  {
    float af[2][8];
#pragma unroll
    for (int c = 0; c < 8; ++c) {
      const int col = lane + 64 * c;
      af[0][c] = af[1][c] = fb1[col];
    }
    for (int k = 0; k < 128; ++k) {
      const float x0 = xn[k], x1 = xn[128 + k];
#pragma unroll
      for (int c = 0; c < 8; ++c) {
        const int col = lane + 64 * c;
        const float w = fW1[k * 512 + col];
        af[0][c] += x0 * w; af[1][c] += x1 * w;
      }
    }
#pragma unroll
    for (int c = 0; c < 8; ++c) {
      const int col = lane + 64 * c;
      hh[col] = gelu_f(af[0][c]);
      hh[512 + col] = gelu_f(af[1][c]);
    }
  }
  __syncthreads();
  {
    float a2[2][2];
#pragma unroll
    for (int c = 0; c < 2; ++c) {
      const int col = lane + 64 * c;
      a2[0][c] = a2[1][c] = fb2[col];
    }
    for (int k = 0; k < 512; ++k) {
      const float h0 = hh[k], h1 = hh[512 + k];
#pragma unroll
      for (int c = 0; c < 2; ++c) {
        const int col = lane + 64 * c;
        const float w = fW2[k * 128 + col];
        a2[0][c] += h0 * w; a2[1][c] += h1 * w;
      }
    }
#pragma unroll
    for (int r = 0; r < 2; ++r) {
      const int row = row0 + r;
      float v0 = xn[r * 128 + lane] + a2[r][0];
      float v1 = xn[r * 128 + lane + 64] + a2[r][1];
      float s = v0 + v1, ss = v0 * v0 + v1 * v1;
#pragma unroll
      for (int off = 1; off < 64; off <<= 1) {
        s += __shfl_xor(s, off, 64);
        ss += __shfl_xor(ss, off, 64);
      }
      const float m = s * (1.f / 128.f);
      const float var = ss * (1.f / 128.f) - m * m;
      const float rs = rsqrtf(var + 1e-5f);
      const float msk = (float)node_mask[row];
      const float o0 = ((v0 - m) * rs * g2[lane] + be2[lane]) * msk;
      const float o1 = ((v1 - m) * rs * g2[lane + 64] + be2[lane + 64]) * msk;
      out_node[row * 128 + lane] = o0;
      out_node[row * 128 + lane + 64] = o1;
      node_bf[row * 128 + lane] = f2bf(o0);
      node_bf[row * 128 + lane + 64] = f2bf(o1);
    }
  }
}

// ---------------------------------------------------------------------------
// u_all[row][n] = dot(node[row], Wu[:,n]) + pfn_b1[n]   (fp32 GEMV)
// ---------------------------------------------------------------------------
__global__ __launch_bounds__(256) void u_kernel(
    const float* __restrict__ out_node, const float* __restrict__ Wu,
    const float* __restrict__ b1, float* __restrict__ u_all) {
  __shared__ float nrow[8][128];
  const int t = threadIdx.x;
  const int r0 = blockIdx.x * 8;
  {
    const int r = t >> 5, c = (t & 31) * 4;
    *(f32x4*)&nrow[r][c] = *(const f32x4*)(out_node + (r0 + r) * 128 + c);
  }
  __syncthreads();
  float acc[8];
  const float bb = b1[t];
#pragma unroll
  for (int r = 0; r < 8; ++r) acc[r] = bb;
  for (int k = 0; k < 128; ++k) {
    const float w = Wu[k * 256 + t];
#pragma unroll
    for (int r = 0; r < 8; ++r) acc[r] += nrow[r][k] * w;
  }
#pragma unroll
  for (int r = 0; r < 8; ++r) u_all[(r0 + r) * 256 + t] = acc[r];
}

// ---------------------------------------------------------------------------
// Fused pair kernel. One WG (512 thr, 8 waves) per 64-row j tile, 80 KB LDS
// (2 blocks/CU). Swapped-operand MFMA so epilogue stores are packed.
// LDS timeline (byte offsets):
//   A   bf16 [64][384] @0      (49152)  feat = [pair | hj | hi*hj], swizzled
//   H1  bf16 [64][256] @0      (32768)  overlays A after GEMM1
//   SCR f32  [64][4][2] @49152 (2048)   LN partial (s,ss), reused for LN2
//   Y   bf16 [64][128] @0      (16384)  overlays H1 after GEMM2
//   H2  bf16 [64][512] @16384  (65536)  after GEMM3 -> total 81920
// All bf16 tiles XOR-swizzled: byte ^= ((row&7)<<4).
// ---------------------------------------------------------------------------
__global__ __launch_bounds__(512, 4) void pair_kernel(
    const float* __restrict__ pair_h, const short* __restrict__ node_bf,
    const int* __restrict__ edge_mask, const short* __restrict__ W1b,
    const short* __restrict__ W2T, const short* __restrict__ W1Tp,
    const short* __restrict__ W2Tp, const float* __restrict__ u_all,
    const float* __restrict__ b2, const float* __restrict__ b1p,
    const float* __restrict__ b2p, const float* __restrict__ g1,
    const float* __restrict__ be1, const float* __restrict__ g2,
    const float* __restrict__ be2, float* __restrict__ out_pair) {
  constexpr int OFF_A = 0, OFF_H1 = 0, OFF_Y = 0, OFF_H2 = 16384,
                OFF_SCR = 49152;
  __shared__ __align__(16) char smem[81920];

  const int t = threadIdx.x;
  const int wg = blockIdx.x;
  const int b = wg >> 10, rem = wg & 1023;
  const int i = rem >> 2, j0 = (rem & 3) << 6;
  const int bi = (b << 8) + i;
  const long rowbase = (long)bi * 256 + j0;

  const int lane = t & 63, wv = t >> 6;
  const int lr = lane & 15, lq = lane >> 4;
  const int swz = (lr & 7) << 4;

  // ---- P0: build A = [pair | hj | hi*hj] bf16, swizzled ----
  {
    const int r = t >> 3, oc = t & 7, c0 = oc * 16;
    const int rsw = (r & 7) << 4;
    const float* prow = pair_h + (rowbase + r) * 128 + c0;
    const short* hjrow = node_bf + (b * 256 + j0 + r) * 128 + c0;
    const short* hirow = node_bf + (b * 256 + i) * 128 + c0;
    char* arow = smem + OFF_A + r * 768;
    s16x8 pr[2], hj[2], hi[2];
#pragma unroll
    for (int h = 0; h < 2; ++h) {
      f32x4 p0 = *(const f32x4*)(prow + h * 8);
      f32x4 p1 = *(const f32x4*)(prow + h * 8 + 4);
      s16x8 sp;
#pragma unroll
      for (int e = 0; e < 4; ++e) { sp[e] = f2bf(p0[e]); sp[e + 4] = f2bf(p1[e]); }
      pr[h] = sp;
      hj[h] = *(const s16x8*)(hjrow + h * 8);
      hi[h] = *(const s16x8*)(hirow + h * 8);
    }
#pragma unroll
    for (int h = 0; h < 2; ++h) {
      *(s16x8*)(arow + ((c0 * 2 + h * 16) ^ rsw)) = pr[h];
      *(s16x8*)(arow + ((256 + c0 * 2 + h * 16) ^ rsw)) = hj[h];
      s16x8 pd;
#pragma unroll
      for (int e = 0; e < 8; ++e) pd[e] = f2bf(bf2f(hi[h][e]) * bf2f(hj[h][e]));
      *(s16x8*)(arow + ((512 + c0 * 2 + h * 16) ^ rsw)) = pd;
    }
  }
  __syncthreads();  // #1

  // ---- GEMM1: C1^T[n][j] over K=384; wave -> n block [wv*32, wv*32+32) ----
  f32x4 acc1[4][2];
#pragma unroll
  for (int jt = 0; jt < 4; ++jt)
#pragma unroll
    for (int nt = 0; nt < 2; ++nt) acc1[jt][nt] = {0.f, 0.f, 0.f, 0.f};
  {
    const int nb = wv * 32;
    const short* wp0 = W1b + (nb + lr) * 384 + lq * 8;
    const short* wp1 = W1b + (nb + 16 + lr) * 384 + lq * 8;
    s16x8 w0 = *(const s16x8*)wp0;
    s16x8 w1 = *(const s16x8*)wp1;
#pragma unroll
    for (int ks = 0; ks < 12; ++ks) {
      s16x8 nw0 = w0, nw1 = w1;
      if (ks < 11) {
        nw0 = *(const s16x8*)(wp0 + (ks + 1) * 32);
        nw1 = *(const s16x8*)(wp1 + (ks + 1) * 32);
      }
      s16x8 d[4];
#pragma unroll
      for (int jt = 0; jt < 4; ++jt)
        d[jt] = *(const s16x8*)(smem + OFF_A +
                                (((jt * 16 + lr) * 768 + ks * 64 + lq * 16) ^ swz));
#pragma unroll
      for (int jt = 0; jt < 4; ++jt) {
        acc1[jt][0] = mfma16(w0, d[jt], acc1[jt][0]);
        acc1[jt][1] = mfma16(w1, d[jt], acc1[jt][1]);
      }
      w0 = nw0; w1 = nw1;
    }
  }
  __syncthreads();  // #2: all A reads done -> H1 may overlay
  {
    const int nb = wv * 32;
#pragma unroll
    for (int nt = 0; nt < 2; ++nt) {
      const int n0 = nb + nt * 16 + lq * 4;
      f32x4 bu = *(const f32x4*)(u_all + bi * 256 + n0);  // includes b1
#pragma unroll
      for (int jt = 0; jt < 4; ++jt) {
        const int j = jt * 16 + lr;
        s16x4 hp;
#pragma unroll
        for (int v = 0; v < 4; ++v) hp[v] = f2bf(gelu_f(acc1[jt][nt][v] + bu[v]));
        *(s16x4*)(smem + OFF_H1 + ((j * 512 + n0 * 2) ^ swz)) = hp;
      }
    }
  }
  __syncthreads();  // #3

  // ---- GEMM2: x1^T[n][j] over K=256; wave -> (jb, nb2) 32x32 ----
  const int jb = (wv >> 2) * 32, nb2 = (wv & 3) * 32;
  f32x4 x1v[2][2];
  {
    f32x4 acc2[2][2];
#pragma unroll
    for (int jt = 0; jt < 2; ++jt)
#pragma unroll
      for (int nt = 0; nt < 2; ++nt) acc2[jt][nt] = {0.f, 0.f, 0.f, 0.f};
    const short* wp0 = W2T + (nb2 + lr) * 256 + lq * 8;
    const short* wp1 = W2T + (nb2 + 16 + lr) * 256 + lq * 8;
    s16x8 w0 = *(const s16x8*)wp0;
    s16x8 w1 = *(const s16x8*)wp1;
#pragma unroll
    for (int ks = 0; ks < 8; ++ks) {
      s16x8 nw0 = w0, nw1 = w1;
      if (ks < 7) {
        nw0 = *(const s16x8*)(wp0 + (ks + 1) * 32);
        nw1 = *(const s16x8*)(wp1 + (ks + 1) * 32);
      }
      s16x8 d[2];
#pragma unroll
      for (int jt = 0; jt < 2; ++jt)
        d[jt] = *(const s16x8*)(smem + OFF_H1 +
                                (((jb + jt * 16 + lr) * 512 + ks * 64 + lq * 16) ^ swz));
#pragma unroll
      for (int jt = 0; jt < 2; ++jt) {
        acc2[jt][0] = mfma16(w0, d[jt], acc2[jt][0]);
        acc2[jt][1] = mfma16(w1, d[jt], acc2[jt][1]);
      }
      w0 = nw0; w1 = nw1;
    }
#pragma unroll
    for (int nt = 0; nt < 2; ++nt) {
      const int n0 = nb2 + nt * 16 + lq * 4;
      f32x4 bv = *(const f32x4*)(b2 + n0);
#pragma unroll
      for (int jt = 0; jt < 2; ++jt) {
        const int j = jb + jt * 16 + lr;
        f32x4 pr = *(const f32x4*)(pair_h + (rowbase + j) * 128 + n0);
        x1v[jt][nt] = acc2[jt][nt] + bv + pr;
      }
    }
  }
  // ---- LN1 in-reg: partials -> SCR -> stats -> write Y bf16 ----
  {
    float s[2], ss[2];
#pragma unroll
    for (int jt = 0; jt < 2; ++jt) {
      s[jt] = 0.f; ss[jt] = 0.f;
#pragma unroll
      for (int nt = 0; nt < 2; ++nt)
#pragma unroll
        for (int v = 0; v < 4; ++v) {
          const float x = x1v[jt][nt][v];
          s[jt] += x; ss[jt] += x * x;
        }
      s[jt] += __shfl_xor(s[jt], 16, 64);
      ss[jt] += __shfl_xor(ss[jt], 16, 64);
      s[jt] += __shfl_xor(s[jt], 32, 64);
      ss[jt] += __shfl_xor(ss[jt], 32, 64);
    }
    if (lq == 0) {
#pragma unroll
      for (int jt = 0; jt < 2; ++jt) {
        const int j = jb + jt * 16 + lr;
        f32x2 p = {s[jt], ss[jt]};
        *(f32x2*)(smem + OFF_SCR + j * 32 + (wv & 3) * 8) = p;
      }
    }
    __syncthreads();  // #4: GEMM2 reads done + partials visible
    float lnm[2], lnr[2];
#pragma unroll
    for (int jt = 0; jt < 2; ++jt) {
      const int j = jb + jt * 16 + lr;
      f32x4 pA = *(const f32x4*)(smem + OFF_SCR + j * 32);
      f32x4 pB = *(const f32x4*)(smem + OFF_SCR + j * 32 + 16);
      const float S = pA[0] + pA[2] + pB[0] + pB[2];
      const float SS = pA[1] + pA[3] + pB[1] + pB[3];
      const float m = S * (1.f / 128.f);
      const float var = SS * (1.f / 128.f) - m * m;
      lnm[jt] = m;
      lnr[jt] = rsqrtf(var + 1e-5f);
    }
#pragma unroll
    for (int nt = 0; nt < 2; ++nt) {
      const int n0 = nb2 + nt * 16 + lq * 4;
      f32x4 gv = *(const f32x4*)(g1 + n0);
      f32x4 bv = *(const f32x4*)(be1 + n0);
#pragma unroll
      for (int jt = 0; jt < 2; ++jt) {
        const int j = jb + jt * 16 + lr;
        s16x4 yp;
#pragma unroll
        for (int v = 0; v < 4; ++v)
          yp[v] = f2bf((x1v[jt][nt][v] - lnm[jt]) * lnr[jt] * gv[v] + bv[v]);
        *(s16x4*)(smem + OFF_Y + ((j * 256 + n0 * 2) ^ swz)) = yp;
      }
    }
  }
  __syncthreads();  // #5

  // ---- GEMM3: H2^T[n][j] over K=128; wave -> 64 n cols, 2 passes of 32 ----
#pragma unroll
  for (int p = 0; p < 2; ++p) {
    f32x4 acc3[4][2];
#pragma unroll
    for (int jt = 0; jt < 4; ++jt)
#pragma unroll
      for (int nt = 0; nt < 2; ++nt) acc3[jt][nt] = {0.f, 0.f, 0.f, 0.f};
    const int nb3 = wv * 64 + p * 32;
    const short* wp0 = W1Tp + (nb3 + lr) * 128 + lq * 8;
    const short* wp1 = W1Tp + (nb3 + 16 + lr) * 128 + lq * 8;
    s16x8 w0 = *(const s16x8*)wp0;
    s16x8 w1 = *(const s16x8*)wp1;
#pragma unroll
    for (int ks = 0; ks < 4; ++ks) {
      s16x8 nw0 = w0, nw1 = w1;
      if (ks < 3) {
        nw0 = *(const s16x8*)(wp0 + (ks + 1) * 32);
        nw1 = *(const s16x8*)(wp1 + (ks + 1) * 32);
      }
      s16x8 d[4];
#pragma unroll
      for (int jt = 0; jt < 4; ++jt)
        d[jt] = *(const s16x8*)(smem + OFF_Y +
                                (((jt * 16 + lr) * 256 + ks * 64 + lq * 16) ^ swz));
#pragma unroll
      for (int jt = 0; jt < 4; ++jt) {
        acc3[jt][0] = mfma16(w0, d[jt], acc3[jt][0]);
        acc3[jt][1] = mfma16(w1, d[jt], acc3[jt][1]);
      }
      w0 = nw0; w1 = nw1;
    }
#pragma unroll
    for (int nt = 0; nt < 2; ++nt) {
      const int n0 = nb3 + nt * 16 + lq * 4;
      f32x4 bv = *(const f32x4*)(b1p + n0);
#pragma unroll
      for (int jt = 0; jt < 4; ++jt) {
        const int j = jt * 16 + lr;
        s16x4 hp;
#pragma unroll
        for (int v = 0; v < 4; ++v) hp[v] = f2bf(gelu_f(acc3[jt][nt][v] + bv[v]));
        *(s16x4*)(smem + OFF_H2 + ((j * 1024 + n0 * 2) ^ swz)) = hp;
      }
    }
  }
  __syncthreads();  // #6

  // ---- GEMM4: x2^T[n][j] over K=512 + y residual ----
  f32x4 x2v[2][2];
  {
    f32x4 acc4[2][2];
#pragma unroll
    for (int jt = 0; jt < 2; ++jt)
#pragma unroll
      for (int nt = 0; nt < 2; ++nt) acc4[jt][nt] = {0.f, 0.f, 0.f, 0.f};
    const short* wp0 = W2Tp + (nb2 + lr) * 512 + lq * 8;
    const short* wp1 = W2Tp + (nb2 + 16 + lr) * 512 + lq * 8;
    s16x8 w0 = *(const s16x8*)wp0;
    s16x8 w1 = *(const s16x8*)wp1;
#pragma unroll
    for (int ks = 0; ks < 16; ++ks) {
      s16x8 nw0 = w0, nw1 = w1;
      if (ks < 15) {
        nw0 = *(const s16x8*)(wp0 + (ks + 1) * 32);
        nw1 = *(const s16x8*)(wp1 + (ks + 1) * 32);
      }
      s16x8 d[2];
#pragma unroll
      for (int jt = 0; jt < 2; ++jt)
        d[jt] = *(const s16x8*)(smem + OFF_H2 +
                                (((jb + jt * 16 + lr) * 1024 + ks * 64 + lq * 16) ^ swz));
#pragma unroll
      for (int jt = 0; jt < 2; ++jt) {
        acc4[jt][0] = mfma16(w0, d[jt], acc4[jt][0]);
        acc4[jt][1] = mfma16(w1, d[jt], acc4[jt][1]);
      }
      w0 = nw0; w1 = nw1;
    }
#pragma unroll
    for (int nt = 0; nt < 2; ++nt) {
      const int n0 = nb2 + nt * 16 + lq * 4;
      f32x4 bv = *(const f32x4*)(b2p + n0);
#pragma unroll
      for (int jt = 0; jt < 2; ++jt) {
        const int j = jb + jt * 16 + lr;
        s16x4 yv = *(const s16x4*)(smem + OFF_Y + ((j * 256 + n0 * 2) ^ swz));
        f32x4 yr;
#pragma unroll
        for (int v = 0; v < 4; ++v) yr[v] = bf2f(yv[v]);
        x2v[jt][nt] = acc4[jt][nt] + bv + yr;
      }
    }
  }
  // ---- LN2 in-reg + edge mask + store ----
  {
    float s[2], ss[2];
#pragma unroll
    for (int jt = 0; jt < 2; ++jt) {
      s[jt] = 0.f; ss[jt] = 0.f;
#pragma unroll
      for (int nt = 0; nt < 2; ++nt)
#pragma unroll
        for (int v = 0; v < 4; ++v) {
          const float x = x2v[jt][nt][v];
          s[jt] += x; ss[jt] += x * x;
        }
      s[jt] += __shfl_xor(s[jt], 16, 64);
      ss[jt] += __shfl_xor(ss[jt], 16, 64);
      s[jt] += __shfl_xor(s[jt], 32, 64);
      ss[jt] += __shfl_xor(ss[jt], 32, 64);
    }
    __syncthreads();  // #7: all H2/Y reads done -> SCR reusable
    if (lq == 0) {
#pragma unroll
      for (int jt = 0; jt < 2; ++jt) {
        const int j = jb + jt * 16 + lr;
        f32x2 p = {s[jt], ss[jt]};
        *(f32x2*)(smem + OFF_SCR + j * 32 + (wv & 3) * 8) = p;
      }
    }
    __syncthreads();  // #8
    float lnm[2], lnr[2], vp[2];
#pragma unroll
    for (int jt = 0; jt < 2; ++jt) {
      const int j = jb + jt * 16 + lr;
      f32x4 pA = *(const f32x4*)(smem + OFF_SCR + j * 32);
      f32x4 pB = *(const f32x4*)(smem + OFF_SCR + j * 32 + 16);
      const float S = pA[0] + pA[2] + pB[0] + pB[2];
      const float SS = pA[1] + pA[3] + pB[1] + pB[3];
      const float m = S * (1.f / 128.f);
      const float var = SS * (1.f / 128.f) - m * m;
      lnm[jt] = m;
      lnr[jt] = rsqrtf(var + 1e-5f);
      vp[jt] = (float)edge_mask[(long)bi * 256 + j0 + j];
    }
#pragma unroll
    for (int nt = 0; nt < 2; ++nt) {
      const int n0 = nb2 + nt * 16 + lq * 4;
      f32x4 gv = *(const f32x4*)(g2 + n0);
      f32x4 bv = *(const f32x4*)(be2 + n0);
#pragma unroll
      for (int jt = 0; jt < 2; ++jt) {
        const int j = jb + jt * 16 + lr;
        f32x4 o;
#pragma unroll
        for (int v = 0; v < 4; ++v)
          o[v] = ((x2v[jt][nt][v] - lnm[jt]) * lnr[jt] * gv[v] + bv[v]) * vp[jt];
        *(f32x4*)(out_pair + (rowbase + j) * 128 + n0) = o;
      }
    }
  }
}

// ---------------------------------------------------------------------------
extern "C" void kernel_launch(void* const* d_in, const int* in_sizes, int n_in,
                              void* d_out, int out_size, void* d_ws,
                              size_t ws_size, hipStream_t stream) {
  const float* node_h = (const float*)d_in[0];
  const float* pair_h = (const float*)d_in[1];
  const int* node_mask = (const int*)d_in[2];
  const int* edge_mask = (const int*)d_in[3];
  const float* nfp_W1 = (const float*)d_in[4];
  const float* nfp_b1 = (const float*)d_in[5];
  const float* nfp_W2 = (const float*)d_in[6];
  const float* nfp_b2 = (const float*)d_in[7];
  const float* pfn_W1 = (const float*)d_in[8];
  const float* pfn_b1 = (const float*)d_in[9];
  const float* pfn_W2 = (const float*)d_in[10];
  const float* pfn_b2 = (const float*)d_in[11];
  const float* nff_W1 = (const float*)d_in[12];
  const float* nff_b1 = (const float*)d_in[13];
  const float* nff_W2 = (const float*)d_in[14];
  const float* nff_b2 = (const float*)d_in[15];
  const float* pff_W1 = (const float*)d_in[16];
  const float* pff_b1 = (const float*)d_in[17];
  const float* pff_W2 = (const float*)d_in[18];
  const float* pff_b2 = (const float*)d_in[19];
  const float* og_W = (const float*)d_in[20];
  const float* og_b = (const float*)d_in[21];
  const float* ig_W = (const float*)d_in[22];
  const float* ig_b = (const float*)d_in[23];
  const float* nn1_g = (const float*)d_in[24];
  const float* nn1_b = (const float*)d_in[25];
  const float* nn2_g = (const float*)d_in[26];
  const float* nn2_b = (const float*)d_in[27];
  const float* pn1_g = (const float*)d_in[28];
  const float* pn1_b = (const float*)d_in[29];
  const float* pn2_g = (const float*)d_in[30];
  const float* pn2_b = (const float*)d_in[31];

  char* ws = (char*)d_ws;
  short* W1b = (short*)(ws);               // 196608
  short* W2T = (short*)(ws + 196608);      // 65536
  short* W1Tp = (short*)(ws + 262144);     // 131072
  short* W2Tp = (short*)(ws + 393216);     // 131072
  float* Wu = (float*)(ws + 524288);       // 131072
  float* out_ctx = (float*)(ws + 655360);  // 524288
  float* in_ctx = (float*)(ws + 1179648);  // 524288
  short* node_bf = (short*)(ws + 1703936); // 262144
  float* u_all = (float*)(ws + 1966080);   // 1048576 -> ends 3014656

  float* out_node = (float*)d_out;
  float* out_pair = (float*)d_out + 131072;

  prep_kernel<<<1152, 256, 0, stream>>>(pfn_W1, pfn_W2, pff_W1, pff_W2, W1b,
                                        Wu, W2T, W1Tp, W2Tp);
  ctx_kernel<<<2048, 256, 0, stream>>>(pair_h, edge_mask, out_ctx, in_ctx);
  node_kernel<<<128, 256, 0, stream>>>(
      node_h, out_ctx, in_ctx, node_mask, og_W, og_b, ig_W, ig_b, nfp_W1,
      nfp_b1, nfp_W2, nfp_b2, nff_W1, nff_b1, nff_W2, nff_b2, nn1_g, nn1_b,
      nn2_g, nn2_b, out_node, node_bf);
  u_kernel<<<128, 256, 0, stream>>>(out_node, Wu, pfn_b1, u_all);
  pair_kernel<<<4096, 512, 0, stream>>>(
      pair_h, node_bf, edge_mask, W1b, W2T, W1Tp, W2Tp, u_all, pfn_b2, pff_b1,
      pff_b2, pn1_g, pn1_b, pn2_g, pn2_b, out_pair);
}